// Round 4
// baseline (3538.291 us; speedup 1.0000x reference)
//
#include <hip/hip_runtime.h>
#include <hip/hip_bf16.h>

// Swin shifted-window attention, B=1, C=96, H=W=512, ws=8, heads=6, shift=4.
// Dtype contract (R3->R4 evidence): ALL INPUTS FLOAT32, OUTPUT FLOAT32.
// Faithful to the reference's raw reshape: the (B,C,H,W) buffer is
// reinterpreted as (H,W,C), rolled by -4 in h/w, reinterpreted back as
// (C,H,W), then window-partitioned. Output is window_reverse only.

namespace {
constexpr int kH = 512, kW = 512, kC = 96;
constexpr int kWS = 8, kN = 64, kNH = 6;
constexpr int kShift = 4;
constexpr int kHW = kH * kW;   // 262144
constexpr int kWC = kW * kC;   // 49152

// LDS pool layout (float offsets) — regions are DISJOINT (no aliasing).
constexpr int XT_STRIDE = 97;                      // xt [64][97] input tile
constexpr int XT_OFF = 0;
constexpr int WS_STRIDE = 52;                      // wS [96][52] weight stage
constexpr int WS_OFF = XT_OFF + 64 * XT_STRIDE;    // 6208
constexpr int QKV_STRIDE = 20;                     // q/k/v [64][20]
constexpr int Q_OFF = WS_OFF + 96 * WS_STRIDE;     // 11200
constexpr int K_OFF = Q_OFF + 64 * QKV_STRIDE;     // 12480
constexpr int V_OFF = K_OFF + 64 * QKV_STRIDE;     // 13760
constexpr int BIAS_OFF = V_OFF + 64 * QKV_STRIDE;  // 15040, 225 floats
constexpr int LAB_OFF = BIAS_OFF + 225;            // 15265, 64 ints
constexpr int POOL = LAB_OFF + 64;                 // 15329 floats = 61316 B
}  // namespace

__global__ __launch_bounds__(256, 2) void swin_window_attn(
    const float* __restrict__ x,
    const float* __restrict__ bias_tab,
    const float* __restrict__ w_qkv,
    const float* __restrict__ b_qkv,
    const float* __restrict__ w_proj,
    const float* __restrict__ b_proj,
    float* __restrict__ out) {
  __shared__ __align__(16) float pool[POOL];
  float* xt = pool + XT_OFF;
  float* wS = pool + WS_OFF;
  float* qS = pool + Q_OFF;
  float* kS = pool + K_OFF;
  float* vS = pool + V_OFF;
  float* biasS = pool + BIAS_OFF;
  int* labS = (int*)(pool + LAB_OFF);

  const int t = threadIdx.x;
  const int win = blockIdx.x;
  const int wh = win >> 6;
  const int wwi = win & 63;
  const int h0 = wh * kWS;
  const int w0 = wwi * kWS;

  // ---- Phase 0: gather window tile through raw-reshape + roll map ----
  for (int e = t; e < kN * kC; e += 256) {
    const int n = e & 63;
    const int c = e >> 6;
    const int hh = h0 + (n >> 3);
    const int ww = w0 + (n & 7);
    const int idx = c * kHW + hh * kW + ww;     // flat idx in (C,H,W) view
    const int hp = idx / kWC;                   // decompose as (H,W,C) view
    const int rem = idx - hp * kWC;
    const int wp = rem / kC;
    const int cp = rem - wp * kC;
    int hs = hp + kShift; if (hs >= kH) hs -= kH;   // roll(-s): out[i]=in[i+s]
    int wsr = wp + kShift; if (wsr >= kW) wsr -= kW;
    xt[n * XT_STRIDE + c] = x[hs * kWC + wsr * kC + cp];
  }
  if (t < kN) {  // shift-mask region label per token (rolled-image coords)
    const int hh = h0 + (t >> 3);
    const int ww = w0 + (t & 7);
    const int lh = (hh < kH - kWS) ? 0 : (hh < kH - kShift ? 1 : 2);
    const int lw = (ww < kW - kWS) ? 0 : (ww < kW - kShift ? 1 : 2);
    labS[t] = lh * 3 + lw;
  }

  const int nown = t >> 2;          // token row owned by this thread
  const int qg = t & 3;             // quarter within the row group
  const int gl = (t & 63) & ~3;     // wave-local base lane of my group
  const int i1 = nown >> 3, j1 = nown & 7;

  float yacc[kNH][4];

#pragma unroll
  for (int h = 0; h < kNH; ++h) {
    // bar A: phase-0 writes visible (h=0); prev head's readers of
    // wS/biasS (QKV/score) and vS (PV) are all done before restage.
    __syncthreads();

    // stage this head's qkv weight slice: wS[c][j], j = mat*16 + d
    for (int e = t; e < 96 * 48; e += 256) {
      const int c = e % 96;
      const int j = e / 96;
      const int row = (j >> 4) * 96 + h * 16 + (j & 15);
      wS[c * WS_STRIDE + j] = w_qkv[row * 96 + c];
    }
    if (t < 225) biasS[t] = bias_tab[t * kNH + h];
    __syncthreads();  // bar B: stage visible

    // ---- QKV: thread computes q/k/v[nown][qg*4 .. +3] ----
    float aq[4], ak[4], av[4];
#pragma unroll
    for (int u = 0; u < 4; ++u) {
      const int d = h * 16 + qg * 4 + u;
      aq[u] = b_qkv[d];
      ak[u] = b_qkv[96 + d];
      av[u] = b_qkv[192 + d];
    }
    for (int c = 0; c < 96; ++c) {
      const float xv = xt[nown * XT_STRIDE + c];
      const float4 wq = *(const float4*)(wS + c * WS_STRIDE + qg * 4);
      const float4 wk = *(const float4*)(wS + c * WS_STRIDE + 16 + qg * 4);
      const float4 wv = *(const float4*)(wS + c * WS_STRIDE + 32 + qg * 4);
      aq[0] += xv * wq.x; aq[1] += xv * wq.y; aq[2] += xv * wq.z; aq[3] += xv * wq.w;
      ak[0] += xv * wk.x; ak[1] += xv * wk.y; ak[2] += xv * wk.z; ak[3] += xv * wk.w;
      av[0] += xv * wv.x; av[1] += xv * wv.y; av[2] += xv * wv.z; av[3] += xv * wv.w;
    }
    // q pre-scaled by hd^-0.5 = 0.25
    *(float4*)(qS + nown * QKV_STRIDE + qg * 4) =
        make_float4(aq[0] * 0.25f, aq[1] * 0.25f, aq[2] * 0.25f, aq[3] * 0.25f);
    *(float4*)(kS + nown * QKV_STRIDE + qg * 4) = make_float4(ak[0], ak[1], ak[2], ak[3]);
    *(float4*)(vS + nown * QKV_STRIDE + qg * 4) = make_float4(av[0], av[1], av[2], av[3]);
    __syncthreads();  // bar C: q/k/v visible to all

    // ---- QK^T + bias + mask; 16 scores per lane, in registers ----
    const float4 qv0 = *(const float4*)(qS + nown * QKV_STRIDE + 0);
    const float4 qv1 = *(const float4*)(qS + nown * QKV_STRIDE + 4);
    const float4 qv2 = *(const float4*)(qS + nown * QKV_STRIDE + 8);
    const float4 qv3 = *(const float4*)(qS + nown * QKV_STRIDE + 12);
    const int labn = labS[nown];
    float sreg[16];
    float mx = -1e30f;
#pragma unroll
    for (int mm = 0; mm < 16; ++mm) {
      const int m = mm * 4 + qg;  // lane's share of the row
      const float4 k0 = *(const float4*)(kS + m * QKV_STRIDE + 0);
      const float4 k1 = *(const float4*)(kS + m * QKV_STRIDE + 4);
      const float4 k2 = *(const float4*)(kS + m * QKV_STRIDE + 8);
      const float4 k3 = *(const float4*)(kS + m * QKV_STRIDE + 12);
      float s = qv0.x * k0.x + qv0.y * k0.y + qv0.z * k0.z + qv0.w * k0.w
              + qv1.x * k1.x + qv1.y * k1.y + qv1.z * k1.z + qv1.w * k1.w
              + qv2.x * k2.x + qv2.y * k2.y + qv2.z * k2.z + qv2.w * k2.w
              + qv3.x * k3.x + qv3.y * k3.y + qv3.z * k3.z + qv3.w * k3.w;
      const int i2 = m >> 3, j2 = m & 7;
      s += biasS[(i1 - i2 + 7) * 15 + (j1 - j2 + 7)];
      s += (labS[m] != labn) ? -100.0f : 0.0f;
      sreg[mm] = s;
      mx = fmaxf(mx, s);
    }
    // row softmax across the 4-lane group (butterfly)
    mx = fmaxf(mx, __shfl_xor(mx, 1));
    mx = fmaxf(mx, __shfl_xor(mx, 2));
    float sum = 0.f;
#pragma unroll
    for (int mm = 0; mm < 16; ++mm) {
      const float e = __expf(sreg[mm] - mx);
      sreg[mm] = e;
      sum += e;
    }
    sum += __shfl_xor(sum, 1);
    sum += __shfl_xor(sum, 2);   // every lane now has the full row sum

    // ---- PV via shuffle: p[m] lives on lane gl+(m&3) at slot m>>2 ----
    float a0 = 0.f, a1 = 0.f, a2 = 0.f, a3 = 0.f;
#pragma unroll
    for (int mm = 0; mm < 16; ++mm) {
#pragma unroll
      for (int src = 0; src < 4; ++src) {
        const float p = __shfl(sreg[mm], gl + src);
        const float4 vv = *(const float4*)(vS + (mm * 4 + src) * QKV_STRIDE + qg * 4);
        a0 += p * vv.x; a1 += p * vv.y; a2 += p * vv.z; a3 += p * vv.w;
      }
    }
    const float inv = 1.0f / sum;
    yacc[h][0] = a0 * inv; yacc[h][1] = a1 * inv;
    yacc[h][2] = a2 * inv; yacc[h][3] = a3 * inv;
  }

  // ---- projection (two 48-column passes) + scatter to (C,H,W) ----
  // y[nown][c] is fetched from the group's yacc registers via shuffle.
  const int hh = h0 + (nown >> 3);
  const int ww = w0 + (nown & 7);
  for (int p = 0; p < 2; ++p) {
    __syncthreads();  // prev wS readers done (QKV h=5 / proj p=0)
    for (int e = t; e < 96 * 48; e += 256) {
      const int c = e % 96;
      const int jl = e / 96;
      wS[c * WS_STRIDE + jl] = w_proj[(p * 48 + jl) * 96 + c];
    }
    __syncthreads();
    float acc[12];
#pragma unroll
    for (int k = 0; k < 12; ++k)
      acc[k] = b_proj[p * 48 + qg * 12 + k];
#pragma unroll
    for (int h2 = 0; h2 < kNH; ++h2)
#pragma unroll
      for (int g = 0; g < 4; ++g)
#pragma unroll
        for (int u = 0; u < 4; ++u) {
          const float yv = __shfl(yacc[h2][u], gl + g);
          const int c = h2 * 16 + g * 4 + u;
#pragma unroll
          for (int k4 = 0; k4 < 12; k4 += 4) {
            const float4 wv = *(const float4*)(wS + c * WS_STRIDE + qg * 12 + k4);
            acc[k4 + 0] += yv * wv.x;
            acc[k4 + 1] += yv * wv.y;
            acc[k4 + 2] += yv * wv.z;
            acc[k4 + 3] += yv * wv.w;
          }
        }
#pragma unroll
    for (int k = 0; k < 12; ++k) {
      const int oc = p * 48 + qg * 12 + k;
      out[oc * kHW + hh * kW + ww] = acc[k];
    }
  }
}

extern "C" void kernel_launch(void* const* d_in, const int* in_sizes, int n_in,
                              void* d_out, int out_size, void* d_ws, size_t ws_size,
                              hipStream_t stream) {
  const float* x  = (const float*)d_in[0];
  const float* bt = (const float*)d_in[1];
  const float* wq = (const float*)d_in[2];
  const float* bq = (const float*)d_in[3];
  const float* wp = (const float*)d_in[4];
  const float* bp = (const float*)d_in[5];
  // d_in[6..8] = window_size/num_heads/shift_size scalars: compile-time here.
  float* out = (float*)d_out;
  swin_window_attn<<<dim3(64 * 64), dim3(256), 0, stream>>>(x, bt, wq, bq, wp, bp, out);
}